// Round 2
// baseline (823.679 us; speedup 1.0000x reference)
//
#include <hip/hip_runtime.h>
#include <hip/hip_bf16.h>

#define EMB 64

__device__ __forceinline__ float bf2f(unsigned short h) {
    return __uint_as_float(((unsigned)h) << 16);
}
__device__ __forceinline__ unsigned short f2bf(float f) {
    unsigned u = __float_as_uint(f);
    unsigned r = (u + 0x7fffu + ((u >> 16) & 1u)) >> 16;  // RNE
    return (unsigned short)r;
}

// ---- K1: user row_ptr (binary search) + item degree histogram, merged ----
__global__ void k1_kernel(const int* __restrict__ row, const int* __restrict__ colh,
                          int* __restrict__ urp, int* __restrict__ degit,
                          int NU, int Eh, int urp_blocks) {
    if ((int)blockIdx.x < urp_blocks) {
        int r = blockIdx.x * blockDim.x + threadIdx.x;
        if (r > NU) return;
        if (r == NU) { urp[NU] = Eh; return; }
        int lo = 0, hi = Eh;
        while (lo < hi) {
            int mid = (lo + hi) >> 1;
            if (row[mid] < r) lo = mid + 1; else hi = mid;
        }
        urp[r] = lo;
    } else {
        int e = (blockIdx.x - urp_blocks) * blockDim.x + threadIdx.x;
        if (e < Eh) atomicAdd(&degit[colh[e] - NU], 1);
    }
}

// ---- exclusive scan over item degrees ----
__global__ void scan1_kernel(const int* __restrict__ deg, int* __restrict__ excl,
                             int* __restrict__ partials, int N) {
    __shared__ int sh[256];
    int b = blockIdx.x, t = threadIdx.x;
    int base = b * 1024 + t * 4;
    int d0 = (base + 0 < N) ? deg[base + 0] : 0;
    int d1 = (base + 1 < N) ? deg[base + 1] : 0;
    int d2 = (base + 2 < N) ? deg[base + 2] : 0;
    int d3 = (base + 3 < N) ? deg[base + 3] : 0;
    int tsum = d0 + d1 + d2 + d3;
    sh[t] = tsum;
    __syncthreads();
    for (int off = 1; off < 256; off <<= 1) {
        int v = (t >= off) ? sh[t - off] : 0;
        __syncthreads();
        sh[t] += v;
        __syncthreads();
    }
    int excl_t = sh[t] - tsum;
    if (base + 0 < N) excl[base + 0] = excl_t;
    if (base + 1 < N) excl[base + 1] = excl_t + d0;
    if (base + 2 < N) excl[base + 2] = excl_t + d0 + d1;
    if (base + 3 < N) excl[base + 3] = excl_t + d0 + d1 + d2;
    if (t == 255) partials[b] = sh[t];
}

__global__ void scan2_kernel(int* __restrict__ partials, int nb) {
    __shared__ int sh[512];
    int t = threadIdx.x;
    int v = (t < nb) ? partials[t] : 0;
    sh[t] = v;
    __syncthreads();
    for (int off = 1; off < 512; off <<= 1) {
        int u = (t >= off) ? sh[t - off] : 0;
        __syncthreads();
        sh[t] += u;
        __syncthreads();
    }
    if (t < nb) partials[t] = sh[t] - v;  // exclusive
}

// ---- K4: scan3 (irp/cursor finalize) + dinv, merged ----
__global__ void k4_kernel(const int* __restrict__ excl, const int* __restrict__ partials,
                          int* __restrict__ irp, int* __restrict__ cursor,
                          const int* __restrict__ urp, const int* __restrict__ degit,
                          float* __restrict__ dinv,
                          int NI, int Eh, int NU, int N, int scan3_blocks) {
    if ((int)blockIdx.x < scan3_blocks) {
        int i = blockIdx.x * blockDim.x + threadIdx.x;
        if (i < NI) {
            int v = excl[i] + partials[i >> 10];
            irp[i] = v;
            cursor[i] = v;
        }
        if (i == NI) irp[NI] = Eh;
    } else {
        int i = (blockIdx.x - scan3_blocks) * blockDim.x + threadIdx.x;
        if (i >= N) return;
        int d = (i < NU) ? (urp[i + 1] - urp[i]) : degit[i - NU];
        dinv[i] = rsqrtf((float)d + 1.0f);
    }
}

// ---- x0 = bf16(concat(user_emb, item_emb)), vectorized float4 -> ushort4 ----
__global__ void init_kernel(const float* __restrict__ u, const float* __restrict__ it,
                            unsigned short* __restrict__ x, long nu_elems, long total) {
    long j4 = ((long)blockIdx.x * blockDim.x + threadIdx.x) * 4;
    if (j4 >= total) return;
    float4 v = (j4 < nu_elems) ? ((const float4*)u)[j4 >> 2]
                               : ((const float4*)it)[(j4 - nu_elems) >> 2];
    ushort4 o;
    o.x = f2bf(v.x); o.y = f2bf(v.y); o.z = f2bf(v.z); o.w = f2bf(v.w);
    ((ushort4*)x)[j4 >> 2] = o;
}

// ---- per-node SpMM body: one 16-lane group per node, 8 edges in flight ----
__device__ __forceinline__ void spmm_node(
    int i, int q,
    const int* __restrict__ urp, const int* __restrict__ irp,
    const int* __restrict__ colg, const int* __restrict__ icols,
    const float* __restrict__ dinv,
    const unsigned short* __restrict__ xc,
    unsigned short* __restrict__ xn,
    const unsigned short* __restrict__ x0b,
    const unsigned short* __restrict__ x1b,
    float* __restrict__ out, int NU) {
    const int* list;
    int s, e;
    if (i < NU) { s = urp[i]; e = urp[i + 1]; list = colg; }
    else        { int j = i - NU; s = irp[j]; e = irp[j + 1]; list = icols; }
    float di = dinv[i];
    const ushort4* __restrict__ xc4 = (const ushort4*)xc;

    long p = (long)i * 16 + q;
    ushort4 sv = xc4[p];  // self row, hoisted

    float ax = 0.f, ay = 0.f, az = 0.f, aw = 0.f;
    for (int k0 = s; k0 < e; k0 += 8) {
        int   c[8];
        float w[8];
#pragma unroll
        for (int j = 0; j < 8; ++j) {
            int k = k0 + j;
            bool v = (k < e);
            c[j] = v ? list[k] : 0;
            w[j] = v ? di * dinv[c[j]] : 0.0f;
        }
        ushort4 u[8];
#pragma unroll
        for (int j = 0; j < 8; ++j) u[j] = xc4[(long)c[j] * 16 + q];  // 8 gathers in flight
#pragma unroll
        for (int j = 0; j < 8; ++j) {
            ax += w[j] * bf2f(u[j].x);
            ay += w[j] * bf2f(u[j].y);
            az += w[j] * bf2f(u[j].z);
            aw += w[j] * bf2f(u[j].w);
        }
    }

    float sw = di * di;
    ax += sw * bf2f(sv.x);
    ay += sw * bf2f(sv.y);
    az += sw * bf2f(sv.z);
    aw += sw * bf2f(sv.w);

    if (xn) {
        ushort4 o;
        o.x = f2bf(ax); o.y = f2bf(ay); o.z = f2bf(az); o.w = f2bf(aw);
        ((ushort4*)xn)[p] = o;
    } else {
        ushort4 a0 = ((const ushort4*)x0b)[p];
        ushort4 a1 = ((const ushort4*)x1b)[p];
        float4 o;
        o.x = bf2f(a0.x) + bf2f(a1.x) + bf2f(sv.x) + ax;
        o.y = bf2f(a0.y) + bf2f(a1.y) + bf2f(sv.y) + ay;
        o.z = bf2f(a0.z) + bf2f(a1.z) + bf2f(sv.z) + az;
        o.w = bf2f(a0.w) + bf2f(a1.w) + bf2f(sv.w) + aw;
        ((float4*)out)[p] = o;
    }
}

// ---- M2: ifill (item CSR scatter) blocks first, then L0-user spmm blocks ----
// ifill is atomic/scatter-wall-bound with idle VALU and 10% HBM; the user half
// of layer 0 (independent of icols) backfills and hides inside it.
__global__ void m2_kernel(const int* __restrict__ rowh, const int* __restrict__ colh,
                          int* __restrict__ cursor, int* __restrict__ icols,
                          int ifill_blocks, int Eh,
                          const int* __restrict__ urp, const int* __restrict__ irp,
                          const int* __restrict__ colg,
                          const float* __restrict__ dinv,
                          const unsigned short* __restrict__ xc,
                          unsigned short* __restrict__ xn, int NU) {
    if ((int)blockIdx.x < ifill_blocks) {
        int e = blockIdx.x * blockDim.x + threadIdx.x;
        if (e < Eh) {
            int u = rowh[e];
            int itl = colh[e] - NU;
            int pos = atomicAdd(&cursor[itl], 1);
            icols[pos] = u;
        }
    } else {
        long t = (long)(blockIdx.x - ifill_blocks) * blockDim.x + threadIdx.x;
        int i = (int)(t >> 4);
        if (i >= NU) return;  // users only: never touches icols
        spmm_node(i, (int)(t & 15), urp, irp, colg, /*icols=*/nullptr, dinv,
                  xc, xn, nullptr, nullptr, nullptr, NU);
    }
}

// ---- generic spmm over node range [base, base+cnt) ----
__global__ void spmm_kernel(int base, int cnt,
                            const int* __restrict__ urp, const int* __restrict__ irp,
                            const int* __restrict__ colg, const int* __restrict__ icols,
                            const float* __restrict__ dinv,
                            const unsigned short* __restrict__ xc,
                            unsigned short* __restrict__ xn,
                            const unsigned short* __restrict__ x0b,
                            const unsigned short* __restrict__ x1b,
                            float* __restrict__ out, int NU) {
    long t = (long)blockIdx.x * blockDim.x + threadIdx.x;
    int r = (int)(t >> 4);
    if (r >= cnt) return;
    spmm_node(base + r, (int)(t & 15), urp, irp, colg, icols, dinv,
              xc, xn, x0b, x1b, out, NU);
}

extern "C" void kernel_launch(void* const* d_in, const int* in_sizes, int n_in,
                              void* d_out, int out_size, void* d_ws, size_t ws_size,
                              hipStream_t stream) {
    const int*   edge_index = (const int*)d_in[0];   // [2, E]
    const float* user_emb   = (const float*)d_in[1]; // [NU, 64]
    const float* item_emb   = (const float*)d_in[2]; // [NI, 64]
    float* out = (float*)d_out;

    const int  E  = in_sizes[0] / 2;
    const int  Eh = E / 2;             // first half: user rows (sorted), cols = items
    const int  NU = in_sizes[1] / EMB;
    const int  NI = in_sizes[2] / EMB;
    const int  N  = NU + NI;
    const long total = (long)N * EMB;

    const int* row = edge_index;       // [E]
    const int* col = edge_index + E;   // [E]
    const int* rowh = row;             // first Eh: sorted user ids
    const int* colh = col;             // first Eh: item ids (random)

    // workspace layout:
    // urp[NU+1] | degit[NI] | excl[NI] | partials[512] | irp[NI+1] | cursor[NI] |
    // icols[Eh] | dinv[N] f | x0[total] bf16 | x1[total] bf16 | x2[total] bf16
    int*   urp      = (int*)d_ws;
    int*   degit    = urp + (NU + 1);
    int*   excl     = degit + NI;
    int*   partials = excl + NI;
    int*   irp      = partials + 512;
    int*   cursor   = irp + (NI + 1);
    int*   icols    = cursor + NI;
    float* dinv     = (float*)(icols + Eh);
    unsigned short* x0 = (unsigned short*)(dinv + N);
    x0 = (unsigned short*)(((uintptr_t)x0 + 15) & ~(uintptr_t)15);
    unsigned short* x1 = x0 + total;
    unsigned short* x2 = x1 + total;

    hipMemsetAsync(degit, 0, (size_t)NI * sizeof(int), stream);

    // K1: urp + ideg
    int urp_blocks  = (NU + 256) / 256;
    int ideg_blocks = (Eh + 255) / 256;
    k1_kernel<<<urp_blocks + ideg_blocks, 256, 0, stream>>>(row, colh, urp, degit,
                                                            NU, Eh, urp_blocks);

    int nb = (NI + 1023) / 1024;  // <= 512
    scan1_kernel<<<nb, 256, 0, stream>>>(degit, excl, partials, NI);
    scan2_kernel<<<1, 512, 0, stream>>>(partials, nb);

    // K4: scan3 + dinv
    int scan3_blocks = (NI + 1 + 255) / 256;
    int dinv_blocks  = (N + 255) / 256;
    k4_kernel<<<scan3_blocks + dinv_blocks, 256, 0, stream>>>(excl, partials, irp, cursor,
                                                              urp, degit, dinv,
                                                              NI, Eh, NU, N, scan3_blocks);

    init_kernel<<<(int)((total / 4 + 255) / 256), 256, 0, stream>>>(user_emb, item_emb, x0,
                                                                    (long)NU * EMB, total);

    // M2: ifill || L0-users (x1[users] = A(x0) over item neighbors)
    int ifill_blocks = (Eh + 255) / 256;
    int ublocks = (int)(((long)NU * 16 + 255) / 256);
    m2_kernel<<<ifill_blocks + ublocks, 256, 0, stream>>>(rowh, colh, cursor, icols,
                                                          ifill_blocks, Eh,
                                                          urp, irp, col, dinv, x0, x1, NU);

    // L0 items: x1[items] = A(x0) over user neighbors (needs icols)
    int iblocks = (int)(((long)NI * 16 + 255) / 256);
    spmm_kernel<<<iblocks, 256, 0, stream>>>(NU, NI, urp, irp, col, icols, dinv,
                                             x0, x1, nullptr, nullptr, nullptr, NU);

    // L1: x2 = A(x1), all nodes
    int ablocks = (int)(((long)N * 16 + 255) / 256);
    spmm_kernel<<<ablocks, 256, 0, stream>>>(0, N, urp, irp, col, icols, dinv,
                                             x1, x2, nullptr, nullptr, nullptr, NU);

    // L2 (fused final): out = x0 + x1 + x2 + A(x2)
    spmm_kernel<<<ablocks, 256, 0, stream>>>(0, N, urp, irp, col, icols, dinv,
                                             x2, nullptr, x0, x1, out, NU);
}

// Round 3
// 751.823 us; speedup vs baseline: 1.0956x; 1.0956x over previous
//
#include <hip/hip_runtime.h>
#include <hip/hip_bf16.h>

#define EMB 64

__device__ __forceinline__ float bf2f(unsigned short h) {
    return __uint_as_float(((unsigned)h) << 16);
}
__device__ __forceinline__ unsigned short f2bf(float f) {
    unsigned u = __float_as_uint(f);
    unsigned r = (u + 0x7fffu + ((u >> 16) & 1u)) >> 16;  // RNE
    return (unsigned short)r;
}

// ---- K1: user row_ptr (binary search) + item degree histogram, merged ----
__global__ void k1_kernel(const int* __restrict__ row, const int* __restrict__ colh,
                          int* __restrict__ urp, int* __restrict__ degit,
                          int NU, int Eh, int urp_blocks) {
    if ((int)blockIdx.x < urp_blocks) {
        int r = blockIdx.x * blockDim.x + threadIdx.x;
        if (r > NU) return;
        if (r == NU) { urp[NU] = Eh; return; }
        int lo = 0, hi = Eh;
        while (lo < hi) {
            int mid = (lo + hi) >> 1;
            if (row[mid] < r) lo = mid + 1; else hi = mid;
        }
        urp[r] = lo;
    } else {
        int e = (blockIdx.x - urp_blocks) * blockDim.x + threadIdx.x;
        if (e < Eh) atomicAdd(&degit[colh[e] - NU], 1);
    }
}

// ---- exclusive scan over item degrees ----
__global__ void scan1_kernel(const int* __restrict__ deg, int* __restrict__ excl,
                             int* __restrict__ partials, int N) {
    __shared__ int sh[256];
    int b = blockIdx.x, t = threadIdx.x;
    int base = b * 1024 + t * 4;
    int d0 = (base + 0 < N) ? deg[base + 0] : 0;
    int d1 = (base + 1 < N) ? deg[base + 1] : 0;
    int d2 = (base + 2 < N) ? deg[base + 2] : 0;
    int d3 = (base + 3 < N) ? deg[base + 3] : 0;
    int tsum = d0 + d1 + d2 + d3;
    sh[t] = tsum;
    __syncthreads();
    for (int off = 1; off < 256; off <<= 1) {
        int v = (t >= off) ? sh[t - off] : 0;
        __syncthreads();
        sh[t] += v;
        __syncthreads();
    }
    int excl_t = sh[t] - tsum;
    if (base + 0 < N) excl[base + 0] = excl_t;
    if (base + 1 < N) excl[base + 1] = excl_t + d0;
    if (base + 2 < N) excl[base + 2] = excl_t + d0 + d1;
    if (base + 3 < N) excl[base + 3] = excl_t + d0 + d1 + d2;
    if (t == 255) partials[b] = sh[t];
}

__global__ void scan2_kernel(int* __restrict__ partials, int nb) {
    __shared__ int sh[512];
    int t = threadIdx.x;
    int v = (t < nb) ? partials[t] : 0;
    sh[t] = v;
    __syncthreads();
    for (int off = 1; off < 512; off <<= 1) {
        int u = (t >= off) ? sh[t - off] : 0;
        __syncthreads();
        sh[t] += u;
        __syncthreads();
    }
    if (t < nb) partials[t] = sh[t] - v;  // exclusive
}

// ---- K4: scan3 (irp/cursor finalize) + dinv, merged ----
__global__ void k4_kernel(const int* __restrict__ excl, const int* __restrict__ partials,
                          int* __restrict__ irp, int* __restrict__ cursor,
                          const int* __restrict__ urp, const int* __restrict__ degit,
                          float* __restrict__ dinv,
                          int NI, int Eh, int NU, int N, int scan3_blocks) {
    if ((int)blockIdx.x < scan3_blocks) {
        int i = blockIdx.x * blockDim.x + threadIdx.x;
        if (i < NI) {
            int v = excl[i] + partials[i >> 10];
            irp[i] = v;
            cursor[i] = v;
        }
        if (i == NI) irp[NI] = Eh;
    } else {
        int i = (blockIdx.x - scan3_blocks) * blockDim.x + threadIdx.x;
        if (i >= N) return;
        int d = (i < NU) ? (urp[i + 1] - urp[i]) : degit[i - NU];
        dinv[i] = rsqrtf((float)d + 1.0f);
    }
}

// ---- fused: multi-pass item-CSR scatter (write-clustered) + x0 init ----
// ifill blocks: register-cache 1024 edges/block once (coalesced), then 8
// passes over item ranges. All ifill blocks are co-resident => passes run
// near-lockstep, confining the scatter's dirty window to ~1MB so lines are
// fully populated while L2-resident (writeback ~= |icols|, not 16x it).
// Order only affects locality: atomicAdd positions are unique regardless.
// init blocks (independent, BW-bound) backfill behind the latency-bound scatter.
__global__ void ifill_init_kernel(const int* __restrict__ rowh, const int* __restrict__ colh,
                                  int* __restrict__ cursor, int* __restrict__ icols,
                                  int Eh, int NU, int NI, int ifill_blocks,
                                  const float* __restrict__ ue, const float* __restrict__ ie,
                                  unsigned short* __restrict__ x, long nu_elems, long total) {
    if ((int)blockIdx.x < ifill_blocks) {
        int t = threadIdx.x;
        long cb = (long)blockIdx.x * 1024;
        int c[4], u[4];
#pragma unroll
        for (int j = 0; j < 4; ++j) {
            long e = cb + j * 256 + t;
            bool v = (e < Eh);
            c[j] = v ? (colh[e] - NU) : -1;   // -1 never matches any pass range
            u[j] = v ? rowh[e] : 0;
        }
        int slice = (NI + 7) >> 3;
        for (int p = 0; p < 8; ++p) {
            int lo = p * slice, hi = lo + slice;
#pragma unroll
            for (int j = 0; j < 4; ++j) {
                if (c[j] >= lo && c[j] < hi) {
                    int pos = atomicAdd(&cursor[c[j]], 1);
                    icols[pos] = u[j];
                }
            }
        }
    } else {
        long j4 = ((long)(blockIdx.x - ifill_blocks) * blockDim.x + threadIdx.x) * 4;
        if (j4 >= total) return;
        float4 v = (j4 < nu_elems) ? ((const float4*)ue)[j4 >> 2]
                                   : ((const float4*)ie)[(j4 - nu_elems) >> 2];
        ushort4 o;
        o.x = f2bf(v.x); o.y = f2bf(v.y); o.z = f2bf(v.z); o.w = f2bf(v.w);
        ((ushort4*)x)[j4 >> 2] = o;
    }
}

// ---- per-node SpMM body: one 16-lane group per node, 8 edges in flight ----
__device__ __forceinline__ void spmm_node(
    int i, int q,
    const int* __restrict__ urp, const int* __restrict__ irp,
    const int* __restrict__ colg, const int* __restrict__ icols,
    const float* __restrict__ dinv,
    const unsigned short* __restrict__ xc,
    unsigned short* __restrict__ xn,
    const unsigned short* __restrict__ x0b,
    const unsigned short* __restrict__ x1b,
    float* __restrict__ out, int NU) {
    const int* list;
    int s, e;
    if (i < NU) { s = urp[i]; e = urp[i + 1]; list = colg; }
    else        { int j = i - NU; s = irp[j]; e = irp[j + 1]; list = icols; }
    float di = dinv[i];
    const ushort4* __restrict__ xc4 = (const ushort4*)xc;

    long p = (long)i * 16 + q;
    ushort4 sv = xc4[p];  // self row, hoisted

    float ax = 0.f, ay = 0.f, az = 0.f, aw = 0.f;
    for (int k0 = s; k0 < e; k0 += 8) {
        int   c[8];
        float w[8];
#pragma unroll
        for (int j = 0; j < 8; ++j) {
            int k = k0 + j;
            bool v = (k < e);
            c[j] = v ? list[k] : 0;
            w[j] = v ? di * dinv[c[j]] : 0.0f;
        }
        ushort4 u[8];
#pragma unroll
        for (int j = 0; j < 8; ++j) u[j] = xc4[(long)c[j] * 16 + q];  // 8 gathers in flight
#pragma unroll
        for (int j = 0; j < 8; ++j) {
            ax += w[j] * bf2f(u[j].x);
            ay += w[j] * bf2f(u[j].y);
            az += w[j] * bf2f(u[j].z);
            aw += w[j] * bf2f(u[j].w);
        }
    }

    float sw = di * di;
    ax += sw * bf2f(sv.x);
    ay += sw * bf2f(sv.y);
    az += sw * bf2f(sv.z);
    aw += sw * bf2f(sv.w);

    if (xn) {
        ushort4 o;
        o.x = f2bf(ax); o.y = f2bf(ay); o.z = f2bf(az); o.w = f2bf(aw);
        ((ushort4*)xn)[p] = o;
    } else {
        ushort4 a0 = ((const ushort4*)x0b)[p];
        ushort4 a1 = ((const ushort4*)x1b)[p];
        float4 o;
        o.x = bf2f(a0.x) + bf2f(a1.x) + bf2f(sv.x) + ax;
        o.y = bf2f(a0.y) + bf2f(a1.y) + bf2f(sv.y) + ay;
        o.z = bf2f(a0.z) + bf2f(a1.z) + bf2f(sv.z) + az;
        o.w = bf2f(a0.w) + bf2f(a1.w) + bf2f(sv.w) + aw;
        ((float4*)out)[p] = o;
    }
}

// ---- spmm over all N nodes ----
__global__ void spmm_kernel(const int* __restrict__ urp, const int* __restrict__ irp,
                            const int* __restrict__ colg, const int* __restrict__ icols,
                            const float* __restrict__ dinv,
                            const unsigned short* __restrict__ xc,
                            unsigned short* __restrict__ xn,
                            const unsigned short* __restrict__ x0b,
                            const unsigned short* __restrict__ x1b,
                            float* __restrict__ out, int NU, int N) {
    long t = (long)blockIdx.x * blockDim.x + threadIdx.x;
    int i = (int)(t >> 4);
    if (i >= N) return;
    spmm_node(i, (int)(t & 15), urp, irp, colg, icols, dinv,
              xc, xn, x0b, x1b, out, NU);
}

extern "C" void kernel_launch(void* const* d_in, const int* in_sizes, int n_in,
                              void* d_out, int out_size, void* d_ws, size_t ws_size,
                              hipStream_t stream) {
    const int*   edge_index = (const int*)d_in[0];   // [2, E]
    const float* user_emb   = (const float*)d_in[1]; // [NU, 64]
    const float* item_emb   = (const float*)d_in[2]; // [NI, 64]
    float* out = (float*)d_out;

    const int  E  = in_sizes[0] / 2;
    const int  Eh = E / 2;             // first half: user rows (sorted), cols = items
    const int  NU = in_sizes[1] / EMB;
    const int  NI = in_sizes[2] / EMB;
    const int  N  = NU + NI;
    const long total = (long)N * EMB;

    const int* row = edge_index;       // [E]
    const int* col = edge_index + E;   // [E]
    const int* rowh = row;             // first Eh: sorted user ids
    const int* colh = col;             // first Eh: item ids (random)

    // workspace layout:
    // urp[NU+1] | degit[NI] | excl[NI] | partials[512] | irp[NI+1] | cursor[NI] |
    // icols[Eh] | dinv[N] f | x0[total] bf16 | x1[total] bf16 | x2[total] bf16
    int*   urp      = (int*)d_ws;
    int*   degit    = urp + (NU + 1);
    int*   excl     = degit + NI;
    int*   partials = excl + NI;
    int*   irp      = partials + 512;
    int*   cursor   = irp + (NI + 1);
    int*   icols    = cursor + NI;
    float* dinv     = (float*)(icols + Eh);
    unsigned short* x0 = (unsigned short*)(dinv + N);
    x0 = (unsigned short*)(((uintptr_t)x0 + 15) & ~(uintptr_t)15);
    unsigned short* x1 = x0 + total;
    unsigned short* x2 = x1 + total;

    hipMemsetAsync(degit, 0, (size_t)NI * sizeof(int), stream);

    // K1: urp + ideg
    int urp_blocks  = (NU + 256) / 256;
    int ideg_blocks = (Eh + 255) / 256;
    k1_kernel<<<urp_blocks + ideg_blocks, 256, 0, stream>>>(row, colh, urp, degit,
                                                            NU, Eh, urp_blocks);

    int nb = (NI + 1023) / 1024;  // <= 512
    scan1_kernel<<<nb, 256, 0, stream>>>(degit, excl, partials, NI);
    scan2_kernel<<<1, 512, 0, stream>>>(partials, nb);

    // K4: scan3 + dinv
    int scan3_blocks = (NI + 1 + 255) / 256;
    int dinv_blocks  = (N + 255) / 256;
    k4_kernel<<<scan3_blocks + dinv_blocks, 256, 0, stream>>>(excl, partials, irp, cursor,
                                                              urp, degit, dinv,
                                                              NI, Eh, NU, N, scan3_blocks);

    // fused: multi-pass ifill + x0 init
    int ifill_blocks = (Eh + 1023) / 1024;                    // 1024 edges per block
    int init_blocks  = (int)((total / 4 + 255) / 256);
    ifill_init_kernel<<<ifill_blocks + init_blocks, 256, 0, stream>>>(
        rowh, colh, cursor, icols, Eh, NU, NI, ifill_blocks,
        user_emb, item_emb, x0, (long)NU * EMB, total);

    int blocks = (int)(((long)N * 16 + 255) / 256);
    // L0: x1 = A(x0)
    spmm_kernel<<<blocks, 256, 0, stream>>>(urp, irp, col, icols, dinv, x0, x1,
                                            nullptr, nullptr, nullptr, NU, N);
    // L1: x2 = A(x1)
    spmm_kernel<<<blocks, 256, 0, stream>>>(urp, irp, col, icols, dinv, x1, x2,
                                            nullptr, nullptr, nullptr, NU, N);
    // L2 (fused final): out = x0 + x1 + x2 + A(x2)
    spmm_kernel<<<blocks, 256, 0, stream>>>(urp, irp, col, icols, dinv, x2, nullptr,
                                            x0, x1, out, NU, N);
}

// Round 4
// 617.627 us; speedup vs baseline: 1.3336x; 1.2173x over previous
//
#include <hip/hip_runtime.h>
#include <hip/hip_bf16.h>

#define EMB 64

__device__ __forceinline__ float bf2f(unsigned short h) {
    return __uint_as_float(((unsigned)h) << 16);
}
__device__ __forceinline__ unsigned short f2bf(float f) {
    unsigned u = __float_as_uint(f);
    unsigned r = (u + 0x7fffu + ((u >> 16) & 1u)) >> 16;  // RNE
    return (unsigned short)r;
}

// ---- K1: user row_ptr (binary search) + item degree histogram, merged ----
__global__ void k1_kernel(const int* __restrict__ row, const int* __restrict__ colh,
                          int* __restrict__ urp, int* __restrict__ degit,
                          int NU, int Eh, int urp_blocks) {
    if ((int)blockIdx.x < urp_blocks) {
        int r = blockIdx.x * blockDim.x + threadIdx.x;
        if (r > NU) return;
        if (r == NU) { urp[NU] = Eh; return; }
        int lo = 0, hi = Eh;
        while (lo < hi) {
            int mid = (lo + hi) >> 1;
            if (row[mid] < r) lo = mid + 1; else hi = mid;
        }
        urp[r] = lo;
    } else {
        int e = (blockIdx.x - urp_blocks) * blockDim.x + threadIdx.x;
        if (e < Eh) atomicAdd(&degit[colh[e] - NU], 1);
    }
}

// ---- K3: scan1 + dinv + y0-init fused (all sections independent) ----
// y0 = bf16(d^-1/2 * x0): pre-scaled rows kill the per-edge dinv gather in spmm.
// init computes its scale inline from urp/degit (no dep on the dinv section).
__global__ void k3_kernel(const int* __restrict__ degit, int* __restrict__ excl,
                          int* __restrict__ partials,
                          const int* __restrict__ urp, float* __restrict__ dinv,
                          const float* __restrict__ ue, const float* __restrict__ ie,
                          unsigned short* __restrict__ y0,
                          int NU, int NI, int N, long nu_elems, long total,
                          int nb_s1, int nb_dv) {
    int b = blockIdx.x;
    if (b < nb_s1) {
        // exclusive-scan pass 1 over item degrees
        __shared__ int sh[256];
        int t = threadIdx.x;
        int base = b * 1024 + t * 4;
        int d0 = (base + 0 < NI) ? degit[base + 0] : 0;
        int d1 = (base + 1 < NI) ? degit[base + 1] : 0;
        int d2 = (base + 2 < NI) ? degit[base + 2] : 0;
        int d3 = (base + 3 < NI) ? degit[base + 3] : 0;
        int tsum = d0 + d1 + d2 + d3;
        sh[t] = tsum;
        __syncthreads();
        for (int off = 1; off < 256; off <<= 1) {
            int v = (t >= off) ? sh[t - off] : 0;
            __syncthreads();
            sh[t] += v;
            __syncthreads();
        }
        int excl_t = sh[t] - tsum;
        if (base + 0 < NI) excl[base + 0] = excl_t;
        if (base + 1 < NI) excl[base + 1] = excl_t + d0;
        if (base + 2 < NI) excl[base + 2] = excl_t + d0 + d1;
        if (base + 3 < NI) excl[base + 3] = excl_t + d0 + d1 + d2;
        if (t == 255) partials[b] = sh[t];
    } else if (b < nb_s1 + nb_dv) {
        int i = (b - nb_s1) * blockDim.x + threadIdx.x;
        if (i >= N) return;
        int d = (i < NU) ? (urp[i + 1] - urp[i]) : degit[i - NU];
        dinv[i] = rsqrtf((float)d + 1.0f);
    } else {
        long j4 = ((long)(b - nb_s1 - nb_dv) * blockDim.x + threadIdx.x) * 4;
        if (j4 >= total) return;
        int node = (int)(j4 >> 6);
        int d = (node < NU) ? (urp[node + 1] - urp[node]) : degit[node - NU];
        float sc = rsqrtf((float)d + 1.0f);
        float4 v = (j4 < nu_elems) ? ((const float4*)ue)[j4 >> 2]
                                   : ((const float4*)ie)[(j4 - nu_elems) >> 2];
        ushort4 o;
        o.x = f2bf(sc * v.x); o.y = f2bf(sc * v.y);
        o.z = f2bf(sc * v.z); o.w = f2bf(sc * v.w);
        ((ushort4*)y0)[j4 >> 2] = o;
    }
}

__global__ void scan2_kernel(int* __restrict__ partials, int nb) {
    __shared__ int sh[512];
    int t = threadIdx.x;
    int v = (t < nb) ? partials[t] : 0;
    sh[t] = v;
    __syncthreads();
    for (int off = 1; off < 512; off <<= 1) {
        int u = (t >= off) ? sh[t - off] : 0;
        __syncthreads();
        sh[t] += u;
        __syncthreads();
    }
    if (t < nb) partials[t] = sh[t] - v;  // exclusive
}

__global__ void scan3_kernel(const int* __restrict__ excl, const int* __restrict__ partials,
                             int* __restrict__ irp, int* __restrict__ cursor, int NI, int Eh) {
    int i = blockIdx.x * blockDim.x + threadIdx.x;
    if (i < NI) {
        int v = excl[i] + partials[i >> 10];
        irp[i] = v;
        cursor[i] = v;
    }
    if (i == NI) irp[NI] = Eh;
}

// ---- per-node SpMM body over pre-scaled y rows: pure gather+add ----
// s = sum_c y[c,:] + y[i,:]
// layers 0..1: y_next[i,:] = bf16(dinv[i]^2 * s)
// final:       out[i,:] = (y0+y1+y2)[i,:] / dinv[i] + dinv[i] * s
__device__ __forceinline__ void spmm_node(
    int i, int q,
    const int* __restrict__ urp, const int* __restrict__ irp,
    const int* __restrict__ colg, const int* __restrict__ icols,
    const float* __restrict__ dinv,
    const unsigned short* __restrict__ yc,
    unsigned short* __restrict__ yn,
    const unsigned short* __restrict__ y0b,
    const unsigned short* __restrict__ y1b,
    float* __restrict__ out, int NU) {
    const int* list;
    int s, e;
    if (i < NU) { s = urp[i]; e = urp[i + 1]; list = colg; }
    else        { int j = i - NU; s = irp[j]; e = irp[j + 1]; list = icols; }
    float di = dinv[i];
    const ushort4* __restrict__ yc4 = (const ushort4*)yc;

    long p = (long)i * 16 + q;
    ushort4 sv = yc4[p];  // self row, hoisted

    float ax = 0.f, ay = 0.f, az = 0.f, aw = 0.f;
    for (int k0 = s; k0 < e; k0 += 8) {
        int   c[8];
        float w[8];
#pragma unroll
        for (int j = 0; j < 8; ++j) {
            int k = k0 + j;
            bool v = (k < e);
            c[j] = v ? list[k] : 0;
            w[j] = v ? 1.0f : 0.0f;
        }
        ushort4 u[8];
#pragma unroll
        for (int j = 0; j < 8; ++j) u[j] = yc4[(long)c[j] * 16 + q];  // 8 gathers in flight
#pragma unroll
        for (int j = 0; j < 8; ++j) {
            ax += w[j] * bf2f(u[j].x);
            ay += w[j] * bf2f(u[j].y);
            az += w[j] * bf2f(u[j].z);
            aw += w[j] * bf2f(u[j].w);
        }
    }

    // self term (weight exactly 1 in y-space)
    ax += bf2f(sv.x);
    ay += bf2f(sv.y);
    az += bf2f(sv.z);
    aw += bf2f(sv.w);

    if (yn) {
        float t = di * di;
        ushort4 o;
        o.x = f2bf(t * ax); o.y = f2bf(t * ay); o.z = f2bf(t * az); o.w = f2bf(t * aw);
        ((ushort4*)yn)[p] = o;
    } else {
        ushort4 a0 = ((const ushort4*)y0b)[p];
        ushort4 a1 = ((const ushort4*)y1b)[p];
        float inv = 1.0f / di;  // sqrt(deg+1)
        float4 o;
        o.x = (bf2f(a0.x) + bf2f(a1.x) + bf2f(sv.x)) * inv + di * ax;
        o.y = (bf2f(a0.y) + bf2f(a1.y) + bf2f(sv.y)) * inv + di * ay;
        o.z = (bf2f(a0.z) + bf2f(a1.z) + bf2f(sv.z)) * inv + di * az;
        o.w = (bf2f(a0.w) + bf2f(a1.w) + bf2f(sv.w)) * inv + di * aw;
        ((float4*)out)[p] = o;
    }
}

// ---- spmm over node range [base, base+cnt) ----
__global__ void spmm_kernel(int base, int cnt,
                            const int* __restrict__ urp, const int* __restrict__ irp,
                            const int* __restrict__ colg, const int* __restrict__ icols,
                            const float* __restrict__ dinv,
                            const unsigned short* __restrict__ yc,
                            unsigned short* __restrict__ yn,
                            const unsigned short* __restrict__ y0b,
                            const unsigned short* __restrict__ y1b,
                            float* __restrict__ out, int NU) {
    long t = (long)blockIdx.x * blockDim.x + threadIdx.x;
    int r = (int)(t >> 4);
    if (r >= cnt) return;
    spmm_node(base + r, (int)(t & 15), urp, irp, colg, icols, dinv,
              yc, yn, y0b, y1b, out, NU);
}

// ---- M6: ifill (8-pass item-CSR scatter) ROUND-ROBIN interleaved with ----
// ---- L0-user spmm (independent of icols). b%4==0 -> ifill, so both     ----
// ---- populations are co-resident from t=0 (fixes round-2 serialization).---
__global__ void m6_kernel(const int* __restrict__ rowh, const int* __restrict__ colh,
                          int* __restrict__ cursor, int* __restrict__ icols,
                          int nb_if, int Eh, int NU, int NI,
                          const int* __restrict__ urp, const int* __restrict__ irp,
                          const int* __restrict__ colg,
                          const float* __restrict__ dinv,
                          const unsigned short* __restrict__ yc,
                          unsigned short* __restrict__ yn) {
    int b = (int)blockIdx.x;
    int fid = -1, usr;
    if (b < 4 * nb_if) {
        if ((b & 3) == 0) { fid = b >> 2; usr = -1; }
        else              { usr = b - (b >> 2) - 1; }
    } else {
        usr = b - nb_if;
    }

    if (fid >= 0) {
        int t = threadIdx.x;
        long cb = (long)fid * 1024;
        int c[4], u[4];
#pragma unroll
        for (int j = 0; j < 4; ++j) {
            long e = cb + j * 256 + t;
            bool v = (e < Eh);
            c[j] = v ? (colh[e] - NU) : -1;
            u[j] = v ? rowh[e] : 0;
        }
        int slice = (NI + 7) >> 3;
        for (int p = 0; p < 8; ++p) {
            int lo = p * slice, hi = lo + slice;
#pragma unroll
            for (int j = 0; j < 4; ++j) {
                if (c[j] >= lo && c[j] < hi) {
                    int pos = atomicAdd(&cursor[c[j]], 1);
                    icols[pos] = u[j];
                }
            }
        }
    } else {
        long t = (long)usr * blockDim.x + threadIdx.x;
        int i = (int)(t >> 4);
        if (i >= NU) return;  // users only: never touches icols
        spmm_node(i, (int)(t & 15), urp, irp, colg, /*icols=*/nullptr, dinv,
                  yc, yn, nullptr, nullptr, nullptr, NU);
    }
}

extern "C" void kernel_launch(void* const* d_in, const int* in_sizes, int n_in,
                              void* d_out, int out_size, void* d_ws, size_t ws_size,
                              hipStream_t stream) {
    const int*   edge_index = (const int*)d_in[0];   // [2, E]
    const float* user_emb   = (const float*)d_in[1]; // [NU, 64]
    const float* item_emb   = (const float*)d_in[2]; // [NI, 64]
    float* out = (float*)d_out;

    const int  E  = in_sizes[0] / 2;
    const int  Eh = E / 2;             // first half: user rows (sorted), cols = items
    const int  NU = in_sizes[1] / EMB;
    const int  NI = in_sizes[2] / EMB;
    const int  N  = NU + NI;
    const long total = (long)N * EMB;

    const int* row = edge_index;       // [E]
    const int* col = edge_index + E;   // [E]
    const int* rowh = row;             // first Eh: sorted user ids
    const int* colh = col;             // first Eh: item ids (random)

    // workspace layout:
    // urp[NU+1] | degit[NI] | excl[NI] | partials[512] | irp[NI+1] | cursor[NI] |
    // icols[Eh] | dinv[N] f | y0[total] bf16 | y1[total] bf16 | y2[total] bf16
    int*   urp      = (int*)d_ws;
    int*   degit    = urp + (NU + 1);
    int*   excl     = degit + NI;
    int*   partials = excl + NI;
    int*   irp      = partials + 512;
    int*   cursor   = irp + (NI + 1);
    int*   icols    = cursor + NI;
    float* dinv     = (float*)(icols + Eh);
    unsigned short* y0 = (unsigned short*)(dinv + N);
    y0 = (unsigned short*)(((uintptr_t)y0 + 15) & ~(uintptr_t)15);
    unsigned short* y1 = y0 + total;
    unsigned short* y2 = y1 + total;

    hipMemsetAsync(degit, 0, (size_t)NI * sizeof(int), stream);

    // K1: urp + ideg
    int urp_blocks  = (NU + 256) / 256;
    int ideg_blocks = (Eh + 255) / 256;
    k1_kernel<<<urp_blocks + ideg_blocks, 256, 0, stream>>>(row, colh, urp, degit,
                                                            NU, Eh, urp_blocks);

    // K3: scan1 + dinv + y0-init
    int nb_s1 = (NI + 1023) / 1024;              // <= 512
    int nb_dv = (N + 255) / 256;
    int nb_in = (int)((total / 4 + 255) / 256);
    k3_kernel<<<nb_s1 + nb_dv + nb_in, 256, 0, stream>>>(degit, excl, partials,
                                                         urp, dinv, user_emb, item_emb, y0,
                                                         NU, NI, N, (long)NU * EMB, total,
                                                         nb_s1, nb_dv);

    scan2_kernel<<<1, 512, 0, stream>>>(partials, nb_s1);
    scan3_kernel<<<(NI + 1 + 255) / 256, 256, 0, stream>>>(excl, partials, irp, cursor,
                                                           NI, Eh);

    // M6: ifill || L0-users (y1[users])
    int nb_if = (Eh + 1023) / 1024;
    int nb_us = (int)(((long)NU * 16 + 255) / 256);
    m6_kernel<<<nb_if + nb_us, 256, 0, stream>>>(rowh, colh, cursor, icols,
                                                 nb_if, Eh, NU, NI,
                                                 urp, irp, col, dinv, y0, y1);

    // L0 items: y1[items] (needs icols)
    int nb_it = (int)(((long)NI * 16 + 255) / 256);
    spmm_kernel<<<nb_it, 256, 0, stream>>>(NU, NI, urp, irp, col, icols, dinv,
                                           y0, y1, nullptr, nullptr, nullptr, NU);

    // L1: y2 = layer(y1), all nodes
    int nb_all = (int)(((long)N * 16 + 255) / 256);
    spmm_kernel<<<nb_all, 256, 0, stream>>>(0, N, urp, irp, col, icols, dinv,
                                            y1, y2, nullptr, nullptr, nullptr, NU);

    // L2 (fused final): out = (y0+y1+y2)/d + d*s
    spmm_kernel<<<nb_all, 256, 0, stream>>>(0, N, urp, irp, col, icols, dinv,
                                            y2, nullptr, y0, y1, out, NU);
}